// Round 3
// baseline (941.040 us; speedup 1.0000x reference)
//
#include <hip/hip_runtime.h>

// ============================================================================
// CascadeRCNN: 3-stage cascade of {pyramid ROI-align -> fc1 -> fc2 -> heads}
//  - Stages 0/1: SPLIT bf16 (hi+lo, 3 MFMA products) fc1/fc2 -> fp32-accurate
//    reg deltas (they feed the discontinuous pyramid-level select).
//  - Stage 2: plain bf16, heads 0,1,2 batched via blockIdx.z.
//  - GEMM: 128x128x32 tile, 4 waves, 16x16x32 bf16 MFMA, global_load_lds
//    width=16, XOR bank-swizzle (R2: conflicts 9.6M -> 0), split-K fp32
//    partials + epilogue reduce.
//  - R3: (a) transpose_convert rewritten: 256x32 LDS tile, float4 LDS reads,
//    ushort4 stores (512B/wave segments; was 2B scalar). (b) split-K sized
//    from actual ws_size: w1t_lo moved last so stage-2 partials span
//    w1t_lo+tail (S2~6 -> 6 blocks/CU; stages 0/1 S01 up to 16).
//    (c) roi_align: float2 loads / ushort2 stores, 2-way position split.
// ============================================================================

#define BM 128
#define BN 128
#define BK 32
#define K1 12544
#define MPAD 1024
#define NROI 1000

typedef __bf16 bf16_t;
typedef bf16_t bf16x8 __attribute__((ext_vector_type(8)));
typedef float f32x4 __attribute__((ext_vector_type(4)));
typedef float f32x2 __attribute__((ext_vector_type(2)));
typedef unsigned short u16x4 __attribute__((ext_vector_type(4)));
typedef unsigned short u16x2 __attribute__((ext_vector_type(2)));

__device__ __forceinline__ unsigned short f2bf(float x) {
  unsigned u = __float_as_uint(x);
  return (unsigned short)((u + 0x7fffu + ((u >> 16) & 1u)) >> 16);
}
__device__ __forceinline__ float bf2f(unsigned short h) {
  return __uint_as_float(((unsigned)h) << 16);
}

__device__ __forceinline__ void gld_lds16(const void* g, void* l) {
  __builtin_amdgcn_global_load_lds(
      (__attribute__((address_space(1))) void*)g,
      (__attribute__((address_space(3))) void*)l, 16, 0, 0);
}

// ---------------------------------------------------------------------------
// GEMM: C_part[s][h][m][n] = A[h](1024 x K) * B[h]^T(Nh x K), bf16 MFMA.
// LDS swizzle: global[row][grp] -> LDS[row][grp ^ ((row>>1)&3)] (16B groups).
// grid: (Mtiles*Ntiles, S, H); block 256.
// ---------------------------------------------------------------------------
template <bool SPLIT>
__global__ __launch_bounds__(256, 4)
void gemm_bf16(const unsigned short* __restrict__ Ah,
               const unsigned short* __restrict__ Al,
               long long strideA_head,
               const unsigned short* __restrict__ Bh,
               const unsigned short* __restrict__ Bl,
               long long strideB_head,
               float* __restrict__ Cpart,
               int Nh, int K, int kcSteps)
{
  __shared__ __align__(16) unsigned short sAh[BM * BK];
  __shared__ __align__(16) unsigned short sBh[BN * BK];
  __shared__ __align__(16) unsigned short sAl[SPLIT ? BM * BK : 8];
  __shared__ __align__(16) unsigned short sBl[SPLIT ? BN * BK : 8];

  const int t = threadIdx.x;
  const int ntile = Nh / BN;
  const int bm = blockIdx.x / ntile;
  const int bn = blockIdx.x % ntile;
  const int s = blockIdx.y;
  const int h = blockIdx.z;
  const int H = gridDim.z;

  const unsigned short* Ab = Ah + (size_t)h * strideA_head + (size_t)bm * BM * K;
  const unsigned short* Bb = Bh + (size_t)h * strideB_head + (size_t)bn * BN * K;
  const unsigned short* Alb = SPLIT ? (Al + (size_t)h * strideA_head + (size_t)bm * BM * K) : (const unsigned short*)0;
  const unsigned short* Blb = SPLIT ? (Bl + (size_t)h * strideB_head + (size_t)bn * BN * K) : (const unsigned short*)0;

  int k0 = s * kcSteps * BK;
  int k1 = min(K, k0 + kcSteps * BK);

  const int srow = t >> 2;                                  // staging row in 64-row half
  const int gsw = ((t & 3) ^ ((srow >> 1) & 3)) * 8;        // swizzled source col group
  const int lane = t & 63;
  const int wv = t >> 6;
  const int wm = (wv >> 1) * 64;
  const int wn = (wv & 1) * 64;
  const int lr = lane & 15;
  const int q = lane >> 4;
  const int sw = (lr >> 1) & 3;                             // frag-read swizzle
  const int cA = (q ^ sw) * 8;                              // swizzled frag col offset

  f32x4 acc[4][4];
  const f32x4 z = {0.f, 0.f, 0.f, 0.f};
#pragma unroll
  for (int i = 0; i < 4; ++i)
#pragma unroll
    for (int j = 0; j < 4; ++j) acc[i][j] = z;

  for (int kk = k0; kk < k1; kk += BK) {
#pragma unroll
    for (int j = 0; j < 2; ++j) {
      int row = j * 64 + srow;
      gld_lds16(Ab + (size_t)row * K + kk + gsw, (char*)sAh + j * 4096 + t * 16);
      gld_lds16(Bb + (size_t)row * K + kk + gsw, (char*)sBh + j * 4096 + t * 16);
      if constexpr (SPLIT) {
        gld_lds16(Alb + (size_t)row * K + kk + gsw, (char*)sAl + j * 4096 + t * 16);
        gld_lds16(Blb + (size_t)row * K + kk + gsw, (char*)sBl + j * 4096 + t * 16);
      }
    }
    __syncthreads();

    bf16x8 af[4], bfr[4];
#pragma unroll
    for (int i = 0; i < 4; ++i) af[i] = *(const bf16x8*)&sAh[(wm + i * 16 + lr) * BK + cA];
#pragma unroll
    for (int j = 0; j < 4; ++j) bfr[j] = *(const bf16x8*)&sBh[(wn + j * 16 + lr) * BK + cA];
#pragma unroll
    for (int i = 0; i < 4; ++i)
#pragma unroll
      for (int j = 0; j < 4; ++j)
        acc[i][j] = __builtin_amdgcn_mfma_f32_16x16x32_bf16(af[i], bfr[j], acc[i][j], 0, 0, 0);

    if constexpr (SPLIT) {
      bf16x8 al[4], bl[4];
#pragma unroll
      for (int i = 0; i < 4; ++i) al[i] = *(const bf16x8*)&sAl[(wm + i * 16 + lr) * BK + cA];
#pragma unroll
      for (int j = 0; j < 4; ++j) bl[j] = *(const bf16x8*)&sBl[(wn + j * 16 + lr) * BK + cA];
#pragma unroll
      for (int i = 0; i < 4; ++i)
#pragma unroll
        for (int j = 0; j < 4; ++j) {
          acc[i][j] = __builtin_amdgcn_mfma_f32_16x16x32_bf16(af[i], bl[j], acc[i][j], 0, 0, 0);
          acc[i][j] = __builtin_amdgcn_mfma_f32_16x16x32_bf16(al[i], bfr[j], acc[i][j], 0, 0, 0);
        }
    }
    __syncthreads();
  }

  float* Cb = Cpart + ((size_t)(s * H + h) * MPAD + (size_t)bm * BM) * Nh + (size_t)bn * BN;
#pragma unroll
  for (int i = 0; i < 4; ++i)
#pragma unroll
    for (int j = 0; j < 4; ++j)
#pragma unroll
      for (int r = 0; r < 4; ++r) {
        int m = wm + i * 16 + q * 4 + r;   // C/D layout: row = quad*4+reg
        int n = wn + j * 16 + lr;          //             col = lane&15
        Cb[(size_t)m * Nh + n] = acc[i][j][r];
      }
}

// ---------------------------------------------------------------------------
// Epilogue: reduce S split-K partials + bias (+relu), emit bf16 hi[,lo][,f32]
// flags: 1=relu, 2=write hi, 4=write lo, 8=write f32
// ---------------------------------------------------------------------------
__global__ void epilogue_kernel(const float* __restrict__ Cpart, int S, int H, int Nh,
                                const float* __restrict__ bias, int nbias,
                                unsigned short* __restrict__ ohi,
                                unsigned short* __restrict__ olo,
                                float* __restrict__ of32, int flags)
{
  size_t idx = (size_t)blockIdx.x * 256 + threadIdx.x;
  size_t total = (size_t)H * MPAD * Nh;
  if (idx >= total) return;
  int n = (int)(idx % Nh);
  int h = (int)(idx / ((size_t)MPAD * Nh));
  float v = 0.f;
  for (int s = 0; s < S; ++s) v += Cpart[(size_t)s * total + idx];
  if (n < nbias) v += bias[(size_t)h * nbias + n];
  if (flags & 1) v = fmaxf(v, 0.f);
  if (flags & 8) of32[idx] = v;
  if (flags & 2) {
    unsigned short hi = f2bf(v);
    ohi[idx] = hi;
    if (flags & 4) olo[idx] = f2bf(v - bf2f(hi));
  }
}

// ---------------------------------------------------------------------------
// Transpose + fp32->bf16 hi/lo: W[H][K][N] -> T[H][N][K].
// 256(k) x 32(n) tile, LDS [n][k] pad 260, float4 LDS reads, ushort4 stores.
// grid (K/256, N/32, H), block 256.
// ---------------------------------------------------------------------------
__global__ __launch_bounds__(256)
void transpose_convert(const float* __restrict__ W,
                       unsigned short* __restrict__ Thi,
                       unsigned short* __restrict__ Tlo,
                       int K, int N, int loHeads)
{
  __shared__ float tile[32][260];
  int kb = blockIdx.x * 256;
  int nb = blockIdx.y * 32;
  int h = blockIdx.z;
  const float* Wb = W + (size_t)h * K * N + (size_t)kb * N + nb;
  int tn = threadIdx.x & 31;
  int tk = threadIdx.x >> 5;  // 0..7
#pragma unroll
  for (int i = 0; i < 32; ++i) {
    int k = tk + i * 8;
    tile[tn][k] = Wb[(size_t)k * N + tn];
  }
  __syncthreads();
  bool wlo = h < loHeads;
  int l = threadIdx.x & 63;
  int ng = threadIdx.x >> 6;  // 0..3
  size_t ob = (size_t)h * N * K + (size_t)nb * K + kb;
#pragma unroll
  for (int i = 0; i < 8; ++i) {
    int n = ng + i * 4;
    f32x4 v = *(const f32x4*)&tile[n][4 * l];
    u16x4 hi;
#pragma unroll
    for (int j = 0; j < 4; ++j) hi[j] = f2bf(v[j]);
    *(u16x4*)&Thi[ob + (size_t)n * K + 4 * l] = hi;
    if (wlo) {
      u16x4 lo;
#pragma unroll
      for (int j = 0; j < 4; ++j) lo[j] = f2bf(v[j] - bf2f(hi[j]));
      *(u16x4*)&Tlo[ob + (size_t)n * K + 4 * l] = lo;
    }
  }
}

// cls_w (3,1024,81) -> w3t (3,128,1024) bf16, rows 81..127 zero. grid (128,3).
__global__ void transpose_cls(const float* __restrict__ W, unsigned short* __restrict__ T)
{
  int n = blockIdx.x, h = blockIdx.y, t = threadIdx.x;
  size_t ob = ((size_t)h * 128 + n) * 1024;
  if (n < 81) {
    for (int k = t; k < 1024; k += 256)
      T[ob + k] = f2bf(W[((size_t)h * 1024 + k) * 81 + n]);
  } else {
    for (int k = t; k < 1024; k += 256) T[ob + k] = 0;
  }
}

// ---------------------------------------------------------------------------
// Pyramid ROI-align: one block per roi; 128 channel-pairs x 2 position groups.
// float2 loads, ushort2 stores.
// ---------------------------------------------------------------------------
__global__ void roi_align_kernel(const float* __restrict__ rois,
                                 const float* __restrict__ P2, const float* __restrict__ P3,
                                 const float* __restrict__ P4, const float* __restrict__ P5,
                                 unsigned short* __restrict__ phi,
                                 unsigned short* __restrict__ plo, int writeLo)
{
  int m = blockIdx.x;
  int t = threadIdx.x;
  int c = (t & 127) * 2;
  int pg = t >> 7;
  const float* rp = rois + m * 4;
  float y1 = rp[0], x1 = rp[1], y2 = rp[2], x2 = rp[3];
  float hh = y2 - y1, ww = x2 - x1;
  float a = sqrtf(fmaxf(hh * ww, 1e-6f)) / 224.0f;
  float lvl = floorf(4.0f + log2f(a));
  lvl = fminf(fmaxf(lvl, 2.0f), 5.0f);
  int i = (int)lvl - 2;
  const float* f = (i == 0) ? P2 : (i == 1) ? P3 : (i == 2) ? P4 : P5;
  int H = 256 >> i;
  float stride = (float)(4 << i);
  float sy1 = y1 / stride, sx1 = x1 / stride;
  float dy = y2 / stride - sy1, dx = x2 / stride - sx1;
  size_t base = (size_t)m * K1 + c;
  for (int p = pg; p < 49; p += 2) {
    int py = p / 7, px = p % 7;
    float ys = sy1 + ((py + 0.5f) / 7.0f) * dy;
    float xs = sx1 + ((px + 0.5f) / 7.0f) * dx;
    float y0f = fminf(fmaxf(floorf(ys), 0.0f), (float)(H - 1));
    float x0f = fminf(fmaxf(floorf(xs), 0.0f), (float)(H - 1));
    int y0 = (int)y0f, x0 = (int)x0f;
    int y1i = min(y0 + 1, H - 1), x1i = min(x0 + 1, H - 1);
    float wy = fminf(fmaxf(ys - y0f, 0.0f), 1.0f);
    float wx = fminf(fmaxf(xs - x0f, 0.0f), 1.0f);
    f32x2 v00 = *(const f32x2*)(f + ((size_t)y0 * H + x0) * 256 + c);
    f32x2 v01 = *(const f32x2*)(f + ((size_t)y0 * H + x1i) * 256 + c);
    f32x2 v10 = *(const f32x2*)(f + ((size_t)y1i * H + x0) * 256 + c);
    f32x2 v11 = *(const f32x2*)(f + ((size_t)y1i * H + x1i) * 256 + c);
    float w00 = (1.f - wy) * (1.f - wx), w01 = (1.f - wy) * wx;
    float w10 = wy * (1.f - wx), w11 = wy * wx;
    f32x2 v = v00 * w00 + v01 * w01 + v10 * w10 + v11 * w11;
    u16x2 hi;
    hi[0] = f2bf(v[0]); hi[1] = f2bf(v[1]);
    *(u16x2*)&phi[base + p * 256] = hi;
    if (writeLo) {
      u16x2 lo;
      lo[0] = f2bf(v[0] - bf2f(hi[0]));
      lo[1] = f2bf(v[1] - bf2f(hi[1]));
      *(u16x2*)&plo[base + p * 256] = lo;
    }
  }
}

// ---------------------------------------------------------------------------
// deltas = (hi+lo h2) @ reg_w + reg_b, then delta2bbox. one block per roi.
// ---------------------------------------------------------------------------
__global__ void reg_delta_kernel(const unsigned short* __restrict__ h2h,
                                 const unsigned short* __restrict__ h2l,
                                 const float* __restrict__ rw, const float* __restrict__ rb,
                                 const float* __restrict__ rin, float* __restrict__ rout)
{
  int m = blockIdx.x, t = threadIdx.x;
  float s0 = 0, s1 = 0, s2 = 0, s3 = 0;
  const unsigned short* hr = h2h + (size_t)m * 1024;
  const unsigned short* lr = h2l + (size_t)m * 1024;
  for (int k = t; k < 1024; k += 256) {
    float hv = bf2f(hr[k]) + bf2f(lr[k]);
    const float* w = rw + (size_t)k * 4;
    s0 += hv * w[0]; s1 += hv * w[1]; s2 += hv * w[2]; s3 += hv * w[3];
  }
#pragma unroll
  for (int o = 32; o > 0; o >>= 1) {
    s0 += __shfl_xor(s0, o, 64);
    s1 += __shfl_xor(s1, o, 64);
    s2 += __shfl_xor(s2, o, 64);
    s3 += __shfl_xor(s3, o, 64);
  }
  __shared__ float part[4][4];
  int w = t >> 6;
  if ((t & 63) == 0) { part[w][0] = s0; part[w][1] = s1; part[w][2] = s2; part[w][3] = s3; }
  __syncthreads();
  if (t == 0) {
    float d0 = (part[0][0] + part[1][0] + part[2][0] + part[3][0] + rb[0]) * 0.1f;
    float d1 = (part[0][1] + part[1][1] + part[2][1] + part[3][1] + rb[1]) * 0.1f;
    float d2 = (part[0][2] + part[1][2] + part[2][2] + part[3][2] + rb[2]) * 0.2f;
    float d3 = (part[0][3] + part[1][3] + part[2][3] + part[3][3] + rb[3]) * 0.2f;
    const float* r = rin + m * 4;
    float y1 = r[0], x1 = r[1], y2 = r[2], x2 = r[3];
    float h = y2 - y1, wd = x2 - x1;
    float cy = y1 + 0.5f * h + d0 * h;
    float cx = x1 + 0.5f * wd + d1 * wd;
    float nh = h * expf(d2);
    float nw = wd * expf(d3);
    float* ro = rout + m * 4;
    ro[0] = fminf(fmaxf(cy - 0.5f * nh, 0.f), 1024.f);
    ro[1] = fminf(fmaxf(cx - 0.5f * nw, 0.f), 1024.f);
    ro[2] = fminf(fmaxf(cy + 0.5f * nh, 0.f), 1024.f);
    ro[3] = fminf(fmaxf(cx + 0.5f * nw, 0.f), 1024.f);
  }
}

// softmax over 81 logits per (roi, head), average 3 heads. block=128 per roi.
__global__ void softmax_avg_kernel(const float* __restrict__ logits, float* __restrict__ out)
{
  int m = blockIdx.x, t = threadIdx.x;
  __shared__ float sh[128];
  float pacc = 0.0f;
  for (int h = 0; h < 3; ++h) {
    float x = (t < 81) ? logits[((size_t)(h * MPAD + m)) * 128 + t] : -3.0e38f;
    sh[t] = x; __syncthreads();
    for (int o = 64; o > 0; o >>= 1) { if (t < o) sh[t] = fmaxf(sh[t], sh[t + o]); __syncthreads(); }
    float mx = sh[0]; __syncthreads();
    float e = (t < 81) ? expf(x - mx) : 0.0f;
    sh[t] = e; __syncthreads();
    for (int o = 64; o > 0; o >>= 1) { if (t < o) sh[t] += sh[t + o]; __syncthreads(); }
    float sum = sh[0]; __syncthreads();
    pacc += e / sum;
  }
  if (t < 81) out[(size_t)m * 81 + t] = pacc / 3.0f;
}

// ===========================================================================
extern "C" void kernel_launch(void* const* d_in, const int* in_sizes, int n_in,
                              void* d_out, int out_size, void* d_ws, size_t ws_size,
                              hipStream_t stream)
{
  const float* P2 = (const float*)d_in[0];
  const float* P3 = (const float*)d_in[1];
  const float* P4 = (const float*)d_in[2];
  const float* P5 = (const float*)d_in[3];
  const float* rois = (const float*)d_in[4];
  const float* fc1_w = (const float*)d_in[5];
  const float* fc1_b = (const float*)d_in[6];
  const float* fc2_w = (const float*)d_in[7];
  const float* fc2_b = (const float*)d_in[8];
  const float* cls_w = (const float*)d_in[9];
  const float* cls_b = (const float*)d_in[10];
  const float* reg_w = (const float*)d_in[11];
  const float* reg_b = (const float*)d_in[12];
  float* out = (float*)d_out;

  char* ws = (char*)d_ws;
  size_t off = 0;
  auto alloc = [&](size_t b) -> char* {
    char* p = ws + off;
    off = (off + b + 255) & ~(size_t)255;
    return p;
  };
  unsigned short* w1t_hi = (unsigned short*)alloc(3ull * 1024 * K1 * 2);
  unsigned short* w2t_hi = (unsigned short*)alloc(3ull * 1024 * 1024 * 2);
  unsigned short* w2t_lo = (unsigned short*)alloc(2ull * 1024 * 1024 * 2);
  unsigned short* w3t    = (unsigned short*)alloc(3ull * 128 * 1024 * 2);
  unsigned short* phi    = (unsigned short*)alloc((size_t)MPAD * K1 * 2);
  unsigned short* plo    = (unsigned short*)alloc((size_t)MPAD * K1 * 2);
  unsigned short* h1_hi  = (unsigned short*)alloc(3ull * MPAD * 1024 * 2);
  unsigned short* h1_lo  = (unsigned short*)alloc((size_t)MPAD * 1024 * 2);
  unsigned short* h2_hi  = (unsigned short*)alloc(3ull * MPAD * 1024 * 2);
  unsigned short* h2_lo  = (unsigned short*)alloc((size_t)MPAD * 1024 * 2);
  float* logitsb         = (float*)alloc(3ull * MPAD * 128 * 4);
  float* r1              = (float*)alloc(16384);
  float* r2              = (float*)alloc(16384);
  // w1t_lo LAST: dead after stage 1, so stage-2 partials reuse it + tail.
  const size_t w1lo_bytes = 2ull * 1024 * K1 * 2;
  unsigned short* w1t_lo = (unsigned short*)alloc(w1lo_bytes);

  const size_t SLAB = (size_t)MPAD * 1024 * 4;  // 4 MiB per (s,h) slice
  size_t tail = (ws_size > off) ? (ws_size - off) : 0;

  // stages 0/1 partials: tail only (w1t_lo/w2t_lo live)
  int S01 = (int)(tail / SLAB);
  if (S01 > 16) S01 = 16;
  if (S01 < 1) S01 = 1;
  int S01b = S01 > 8 ? 8 : S01;  // fc2 (K=1024, 32 K-tiles)
  float* cpart01 = (float*)(ws + off);
  // stage-2 partials: w1t_lo region + tail (contiguous)
  size_t cap2 = w1lo_bytes + tail;
  int S2 = (int)(cap2 / (3 * SLAB));
  if (S2 > 8) S2 = 8;
  if (S2 < 1) S2 = 1;
  float* cpart2 = (float*)w1t_lo;

  const int fc1Steps01 = (392 + S01 - 1) / S01;
  const int fc2Steps01 = (32 + S01b - 1) / S01b;
  const int fc1Steps2 = (392 + S2 - 1) / S2;

  const long long hs1 = (long long)1024 * K1;
  const long long hs2 = (long long)1024 * 1024;

  dim3 b256(256);

  // --- weight conversion (per call) ---
  hipLaunchKernelGGL(transpose_convert, dim3(K1 / 256, 32, 3), b256, 0, stream,
                     fc1_w, w1t_hi, w1t_lo, K1, 1024, 2);
  hipLaunchKernelGGL(transpose_convert, dim3(4, 32, 3), b256, 0, stream,
                     fc2_w, w2t_hi, w2t_lo, 1024, 1024, 2);
  hipLaunchKernelGGL(transpose_cls, dim3(128, 3), b256, 0, stream, cls_w, w3t);
  hipMemsetAsync(phi + (size_t)NROI * K1, 0, (size_t)(MPAD - NROI) * K1 * 2, stream);
  hipMemsetAsync(plo + (size_t)NROI * K1, 0, (size_t)(MPAD - NROI) * K1 * 2, stream);

  // --- stages 0,1: split-precision path, deltas only ---
  for (int st = 0; st < 2; ++st) {
    const float* rin = (st == 0) ? rois : r1;
    float* rout = (st == 0) ? r1 : r2;
    hipLaunchKernelGGL(roi_align_kernel, dim3(NROI), b256, 0, stream,
                       rin, P2, P3, P4, P5, phi, plo, 1);
    hipLaunchKernelGGL((gemm_bf16<true>), dim3(64, S01, 1), b256, 0, stream,
                       phi, plo, 0LL,
                       w1t_hi + (size_t)st * hs1, w1t_lo + (size_t)st * hs1, 0LL,
                       cpart01, 1024, K1, fc1Steps01);
    hipLaunchKernelGGL(epilogue_kernel, dim3(4096), b256, 0, stream,
                       cpart01, S01, 1, 1024, fc1_b + st * 1024, 1024,
                       h1_hi, h1_lo, (float*)0, 1 | 2 | 4);
    hipLaunchKernelGGL((gemm_bf16<true>), dim3(64, S01b, 1), b256, 0, stream,
                       h1_hi, h1_lo, 0LL,
                       w2t_hi + (size_t)st * hs2, w2t_lo + (size_t)st * hs2, 0LL,
                       cpart01, 1024, 1024, fc2Steps01);
    hipLaunchKernelGGL(epilogue_kernel, dim3(4096), b256, 0, stream,
                       cpart01, S01b, 1, 1024, fc2_b + st * 1024, 1024,
                       h2_hi, h2_lo, (float*)0, 1 | 2 | 4);
    hipLaunchKernelGGL(reg_delta_kernel, dim3(NROI), b256, 0, stream,
                       h2_hi, h2_lo, reg_w + (size_t)st * 1024 * 4, reg_b + st * 4,
                       rin, rout);
  }

  // --- stage 2: plain bf16, heads 0,1,2 batched via blockIdx.z ---
  hipLaunchKernelGGL(roi_align_kernel, dim3(NROI), b256, 0, stream,
                     r2, P2, P3, P4, P5, phi, plo, 0);
  hipLaunchKernelGGL((gemm_bf16<false>), dim3(64, S2, 3), b256, 0, stream,
                     phi, (const unsigned short*)0, 0LL,
                     w1t_hi, (const unsigned short*)0, hs1,
                     cpart2, 1024, K1, fc1Steps2);
  hipLaunchKernelGGL(epilogue_kernel, dim3(12288), b256, 0, stream,
                     cpart2, S2, 3, 1024, fc1_b, 1024,
                     h1_hi, (unsigned short*)0, (float*)0, 1 | 2);
  int S2f = S2 > 8 ? 8 : S2;
  hipLaunchKernelGGL((gemm_bf16<false>), dim3(64, S2f, 3), b256, 0, stream,
                     h1_hi, (const unsigned short*)0, hs2,
                     w2t_hi, (const unsigned short*)0, hs2,
                     cpart2, 1024, 1024, (32 + S2f - 1) / S2f);
  hipLaunchKernelGGL(epilogue_kernel, dim3(12288), b256, 0, stream,
                     cpart2, S2f, 3, 1024, fc2_b, 1024,
                     h2_hi, (unsigned short*)0, (float*)0, 1 | 2);
  // cls: N=128 (81 real + pad), S=8 -> 192 blocks, 4 steps; needs 12 MB
  hipLaunchKernelGGL((gemm_bf16<false>), dim3(8, 8, 3), b256, 0, stream,
                     h2_hi, (const unsigned short*)0, hs2,
                     w3t, (const unsigned short*)0, (long long)128 * 1024,
                     cpart2, 128, 1024, 4);
  hipLaunchKernelGGL(epilogue_kernel, dim3(1536), b256, 0, stream,
                     cpart2, 8, 3, 128, cls_b, 81,
                     (unsigned short*)0, (unsigned short*)0, logitsb, 8);
  hipLaunchKernelGGL(softmax_avg_kernel, dim3(NROI), dim3(128), 0, stream,
                     logitsb, out);
}

// Round 4
// 846.154 us; speedup vs baseline: 1.1121x; 1.1121x over previous
//
#include <hip/hip_runtime.h>

// ============================================================================
// CascadeRCNN: 3-stage cascade of {pyramid ROI-align -> fc1 -> fc2 -> heads}
//  - Stages 0/1: SPLIT bf16 (hi+lo, 3 MFMA products) fc1/fc2 -> fp32-accurate
//    reg deltas (they feed the discontinuous pyramid-level select).
//  - Stage 2: plain bf16, heads 0,1,2 batched via blockIdx.z.
//  - GEMM: 128x128x32 tile, 4 waves, 16x16x32 bf16 MFMA, global_load_lds
//    width=16, XOR bank-swizzle (conflicts = 0), split-K fp32 partials.
//  - R4: split-K reverted to R2 sweet spot (S01=8, S2=4; R3's S=8/16 doubled
//    partial traffic + thrashed L2: FETCH 140->330MB, gemm 117->139us).
//    Fused epilogue+reg_delta (stages 0/1) and cls-epilogue+softmax.
//    Epilogue vectorized x4.
// ============================================================================

#define BM 128
#define BN 128
#define BK 32
#define K1 12544
#define MPAD 1024
#define NROI 1000

typedef __bf16 bf16_t;
typedef bf16_t bf16x8 __attribute__((ext_vector_type(8)));
typedef float f32x4 __attribute__((ext_vector_type(4)));
typedef float f32x2 __attribute__((ext_vector_type(2)));
typedef unsigned short u16x4 __attribute__((ext_vector_type(4)));
typedef unsigned short u16x2 __attribute__((ext_vector_type(2)));

__device__ __forceinline__ unsigned short f2bf(float x) {
  unsigned u = __float_as_uint(x);
  return (unsigned short)((u + 0x7fffu + ((u >> 16) & 1u)) >> 16);
}
__device__ __forceinline__ float bf2f(unsigned short h) {
  return __uint_as_float(((unsigned)h) << 16);
}

__device__ __forceinline__ void gld_lds16(const void* g, void* l) {
  __builtin_amdgcn_global_load_lds(
      (__attribute__((address_space(1))) void*)g,
      (__attribute__((address_space(3))) void*)l, 16, 0, 0);
}

// ---------------------------------------------------------------------------
// GEMM: C_part[s][h][m][n] = A[h](1024 x K) * B[h]^T(Nh x K), bf16 MFMA.
// LDS swizzle: global[row][grp] -> LDS[row][grp ^ ((row>>1)&3)] (16B groups).
// grid: (Mtiles*Ntiles, S, H); block 256.
// ---------------------------------------------------------------------------
template <bool SPLIT>
__global__ __launch_bounds__(256, 4)
void gemm_bf16(const unsigned short* __restrict__ Ah,
               const unsigned short* __restrict__ Al,
               long long strideA_head,
               const unsigned short* __restrict__ Bh,
               const unsigned short* __restrict__ Bl,
               long long strideB_head,
               float* __restrict__ Cpart,
               int Nh, int K, int kcSteps)
{
  __shared__ __align__(16) unsigned short sAh[BM * BK];
  __shared__ __align__(16) unsigned short sBh[BN * BK];
  __shared__ __align__(16) unsigned short sAl[SPLIT ? BM * BK : 8];
  __shared__ __align__(16) unsigned short sBl[SPLIT ? BN * BK : 8];

  const int t = threadIdx.x;
  const int ntile = Nh / BN;
  const int bm = blockIdx.x / ntile;
  const int bn = blockIdx.x % ntile;
  const int s = blockIdx.y;
  const int h = blockIdx.z;
  const int H = gridDim.z;

  const unsigned short* Ab = Ah + (size_t)h * strideA_head + (size_t)bm * BM * K;
  const unsigned short* Bb = Bh + (size_t)h * strideB_head + (size_t)bn * BN * K;
  const unsigned short* Alb = SPLIT ? (Al + (size_t)h * strideA_head + (size_t)bm * BM * K) : (const unsigned short*)0;
  const unsigned short* Blb = SPLIT ? (Bl + (size_t)h * strideB_head + (size_t)bn * BN * K) : (const unsigned short*)0;

  int k0 = s * kcSteps * BK;
  int k1 = min(K, k0 + kcSteps * BK);

  const int srow = t >> 2;                                  // staging row in 64-row half
  const int gsw = ((t & 3) ^ ((srow >> 1) & 3)) * 8;        // swizzled source col group
  const int lane = t & 63;
  const int wv = t >> 6;
  const int wm = (wv >> 1) * 64;
  const int wn = (wv & 1) * 64;
  const int lr = lane & 15;
  const int q = lane >> 4;
  const int sw = (lr >> 1) & 3;                             // frag-read swizzle
  const int cA = (q ^ sw) * 8;                              // swizzled frag col offset

  f32x4 acc[4][4];
  const f32x4 z = {0.f, 0.f, 0.f, 0.f};
#pragma unroll
  for (int i = 0; i < 4; ++i)
#pragma unroll
    for (int j = 0; j < 4; ++j) acc[i][j] = z;

  for (int kk = k0; kk < k1; kk += BK) {
#pragma unroll
    for (int j = 0; j < 2; ++j) {
      int row = j * 64 + srow;
      gld_lds16(Ab + (size_t)row * K + kk + gsw, (char*)sAh + j * 4096 + t * 16);
      gld_lds16(Bb + (size_t)row * K + kk + gsw, (char*)sBh + j * 4096 + t * 16);
      if constexpr (SPLIT) {
        gld_lds16(Alb + (size_t)row * K + kk + gsw, (char*)sAl + j * 4096 + t * 16);
        gld_lds16(Blb + (size_t)row * K + kk + gsw, (char*)sBl + j * 4096 + t * 16);
      }
    }
    __syncthreads();

    bf16x8 af[4], bfr[4];
#pragma unroll
    for (int i = 0; i < 4; ++i) af[i] = *(const bf16x8*)&sAh[(wm + i * 16 + lr) * BK + cA];
#pragma unroll
    for (int j = 0; j < 4; ++j) bfr[j] = *(const bf16x8*)&sBh[(wn + j * 16 + lr) * BK + cA];
#pragma unroll
    for (int i = 0; i < 4; ++i)
#pragma unroll
      for (int j = 0; j < 4; ++j)
        acc[i][j] = __builtin_amdgcn_mfma_f32_16x16x32_bf16(af[i], bfr[j], acc[i][j], 0, 0, 0);

    if constexpr (SPLIT) {
      bf16x8 al[4], bl[4];
#pragma unroll
      for (int i = 0; i < 4; ++i) al[i] = *(const bf16x8*)&sAl[(wm + i * 16 + lr) * BK + cA];
#pragma unroll
      for (int j = 0; j < 4; ++j) bl[j] = *(const bf16x8*)&sBl[(wn + j * 16 + lr) * BK + cA];
#pragma unroll
      for (int i = 0; i < 4; ++i)
#pragma unroll
        for (int j = 0; j < 4; ++j) {
          acc[i][j] = __builtin_amdgcn_mfma_f32_16x16x32_bf16(af[i], bl[j], acc[i][j], 0, 0, 0);
          acc[i][j] = __builtin_amdgcn_mfma_f32_16x16x32_bf16(al[i], bfr[j], acc[i][j], 0, 0, 0);
        }
    }
    __syncthreads();
  }

  float* Cb = Cpart + ((size_t)(s * H + h) * MPAD + (size_t)bm * BM) * Nh + (size_t)bn * BN;
#pragma unroll
  for (int i = 0; i < 4; ++i)
#pragma unroll
    for (int j = 0; j < 4; ++j)
#pragma unroll
      for (int r = 0; r < 4; ++r) {
        int m = wm + i * 16 + q * 4 + r;   // C/D layout: row = quad*4+reg
        int n = wn + j * 16 + lr;          //             col = lane&15
        Cb[(size_t)m * Nh + n] = acc[i][j][r];
      }
}

// ---------------------------------------------------------------------------
// Epilogue (x4 vectorized): v = relu(sum_s partial + bias), emit bf16 hi[,lo].
// bias is full Nh-wide per head. flags: 4 = also write lo plane.
// ---------------------------------------------------------------------------
__global__ __launch_bounds__(256)
void epilogue_kernel(const float* __restrict__ Cpart, int S, int H, int Nh,
                     const float* __restrict__ bias,
                     unsigned short* __restrict__ ohi,
                     unsigned short* __restrict__ olo, int flags)
{
  size_t total = (size_t)H * MPAD * Nh;
  size_t idx = ((size_t)blockIdx.x * 256 + threadIdx.x) * 4;
  if (idx >= total) return;
  int n = (int)(idx % Nh);
  int h = (int)(idx / ((size_t)MPAD * Nh));
  f32x4 v = *(const f32x4*)&bias[(size_t)h * Nh + n];
  for (int s = 0; s < S; ++s) v += *(const f32x4*)&Cpart[(size_t)s * total + idx];
  u16x4 hi, lo;
#pragma unroll
  for (int j = 0; j < 4; ++j) {
    float x = fmaxf(v[j], 0.f);
    hi[j] = f2bf(x);
    lo[j] = f2bf(x - bf2f(hi[j]));
  }
  *(u16x4*)&ohi[idx] = hi;
  if (flags & 4) *(u16x4*)&olo[idx] = lo;
}

// ---------------------------------------------------------------------------
// Transpose + fp32->bf16 hi/lo: W[H][K][N] -> T[H][N][K].
// 256(k) x 32(n) tile, LDS [n][k] pad 260, float4 LDS reads, ushort4 stores.
// ---------------------------------------------------------------------------
__global__ __launch_bounds__(256)
void transpose_convert(const float* __restrict__ W,
                       unsigned short* __restrict__ Thi,
                       unsigned short* __restrict__ Tlo,
                       int K, int N, int loHeads)
{
  __shared__ float tile[32][260];
  int kb = blockIdx.x * 256;
  int nb = blockIdx.y * 32;
  int h = blockIdx.z;
  const float* Wb = W + (size_t)h * K * N + (size_t)kb * N + nb;
  int tn = threadIdx.x & 31;
  int tk = threadIdx.x >> 5;  // 0..7
#pragma unroll
  for (int i = 0; i < 32; ++i) {
    int k = tk + i * 8;
    tile[tn][k] = Wb[(size_t)k * N + tn];
  }
  __syncthreads();
  bool wlo = h < loHeads;
  int l = threadIdx.x & 63;
  int ng = threadIdx.x >> 6;  // 0..3
  size_t ob = (size_t)h * N * K + (size_t)nb * K + kb;
#pragma unroll
  for (int i = 0; i < 8; ++i) {
    int n = ng + i * 4;
    f32x4 v = *(const f32x4*)&tile[n][4 * l];
    u16x4 hi;
#pragma unroll
    for (int j = 0; j < 4; ++j) hi[j] = f2bf(v[j]);
    *(u16x4*)&Thi[ob + (size_t)n * K + 4 * l] = hi;
    if (wlo) {
      u16x4 lo;
#pragma unroll
      for (int j = 0; j < 4; ++j) lo[j] = f2bf(v[j] - bf2f(hi[j]));
      *(u16x4*)&Tlo[ob + (size_t)n * K + 4 * l] = lo;
    }
  }
}

// cls_w (3,1024,81) -> w3t (3,128,1024) bf16, rows 81..127 zero. grid (128,3).
__global__ void transpose_cls(const float* __restrict__ W, unsigned short* __restrict__ T)
{
  int n = blockIdx.x, h = blockIdx.y, t = threadIdx.x;
  size_t ob = ((size_t)h * 128 + n) * 1024;
  if (n < 81) {
    for (int k = t; k < 1024; k += 256)
      T[ob + k] = f2bf(W[((size_t)h * 1024 + k) * 81 + n]);
  } else {
    for (int k = t; k < 1024; k += 256) T[ob + k] = 0;
  }
}

// ---------------------------------------------------------------------------
// Pyramid ROI-align: one block per roi; 128 channel-pairs x 2 position groups.
// ---------------------------------------------------------------------------
__global__ void roi_align_kernel(const float* __restrict__ rois,
                                 const float* __restrict__ P2, const float* __restrict__ P3,
                                 const float* __restrict__ P4, const float* __restrict__ P5,
                                 unsigned short* __restrict__ phi,
                                 unsigned short* __restrict__ plo, int writeLo)
{
  int m = blockIdx.x;
  int t = threadIdx.x;
  int c = (t & 127) * 2;
  int pg = t >> 7;
  const float* rp = rois + m * 4;
  float y1 = rp[0], x1 = rp[1], y2 = rp[2], x2 = rp[3];
  float hh = y2 - y1, ww = x2 - x1;
  float a = sqrtf(fmaxf(hh * ww, 1e-6f)) / 224.0f;
  float lvl = floorf(4.0f + log2f(a));
  lvl = fminf(fmaxf(lvl, 2.0f), 5.0f);
  int i = (int)lvl - 2;
  const float* f = (i == 0) ? P2 : (i == 1) ? P3 : (i == 2) ? P4 : P5;
  int H = 256 >> i;
  float stride = (float)(4 << i);
  float sy1 = y1 / stride, sx1 = x1 / stride;
  float dy = y2 / stride - sy1, dx = x2 / stride - sx1;
  size_t base = (size_t)m * K1 + c;
  for (int p = pg; p < 49; p += 2) {
    int py = p / 7, px = p % 7;
    float ys = sy1 + ((py + 0.5f) / 7.0f) * dy;
    float xs = sx1 + ((px + 0.5f) / 7.0f) * dx;
    float y0f = fminf(fmaxf(floorf(ys), 0.0f), (float)(H - 1));
    float x0f = fminf(fmaxf(floorf(xs), 0.0f), (float)(H - 1));
    int y0 = (int)y0f, x0 = (int)x0f;
    int y1i = min(y0 + 1, H - 1), x1i = min(x0 + 1, H - 1);
    float wy = fminf(fmaxf(ys - y0f, 0.0f), 1.0f);
    float wx = fminf(fmaxf(xs - x0f, 0.0f), 1.0f);
    f32x2 v00 = *(const f32x2*)(f + ((size_t)y0 * H + x0) * 256 + c);
    f32x2 v01 = *(const f32x2*)(f + ((size_t)y0 * H + x1i) * 256 + c);
    f32x2 v10 = *(const f32x2*)(f + ((size_t)y1i * H + x0) * 256 + c);
    f32x2 v11 = *(const f32x2*)(f + ((size_t)y1i * H + x1i) * 256 + c);
    float w00 = (1.f - wy) * (1.f - wx), w01 = (1.f - wy) * wx;
    float w10 = wy * (1.f - wx), w11 = wy * wx;
    f32x2 v = v00 * w00 + v01 * w01 + v10 * w10 + v11 * w11;
    u16x2 hi;
    hi[0] = f2bf(v[0]); hi[1] = f2bf(v[1]);
    *(u16x2*)&phi[base + p * 256] = hi;
    if (writeLo) {
      u16x2 lo;
      lo[0] = f2bf(v[0] - bf2f(hi[0]));
      lo[1] = f2bf(v[1] - bf2f(hi[1]));
      *(u16x2*)&plo[base + p * 256] = lo;
    }
  }
}

// ---------------------------------------------------------------------------
// FUSED fc2-epilogue + reg head + delta2bbox. Reads fc2 split-K partials
// directly: h2[n] = relu(sum_s cpart[(s*1024+m)*1024+n] + fc2_b[n]).
// One block per roi, 256 threads.
// ---------------------------------------------------------------------------
__global__ void reg_delta_kernel(const float* __restrict__ Cpart, int S,
                                 const float* __restrict__ fb,
                                 const float* __restrict__ rw, const float* __restrict__ rb,
                                 const float* __restrict__ rin, float* __restrict__ rout)
{
  int m = blockIdx.x, t = threadIdx.x;
  float s0 = 0, s1 = 0, s2 = 0, s3 = 0;
  for (int n = t; n < 1024; n += 256) {
    float v = fb[n];
    for (int s = 0; s < S; ++s) v += Cpart[((size_t)s * 1024 + m) * 1024 + n];
    v = fmaxf(v, 0.f);
    const float* w = rw + (size_t)n * 4;
    s0 += v * w[0]; s1 += v * w[1]; s2 += v * w[2]; s3 += v * w[3];
  }
#pragma unroll
  for (int o = 32; o > 0; o >>= 1) {
    s0 += __shfl_xor(s0, o, 64);
    s1 += __shfl_xor(s1, o, 64);
    s2 += __shfl_xor(s2, o, 64);
    s3 += __shfl_xor(s3, o, 64);
  }
  __shared__ float part[4][4];
  int w = t >> 6;
  if ((t & 63) == 0) { part[w][0] = s0; part[w][1] = s1; part[w][2] = s2; part[w][3] = s3; }
  __syncthreads();
  if (t == 0) {
    float d0 = (part[0][0] + part[1][0] + part[2][0] + part[3][0] + rb[0]) * 0.1f;
    float d1 = (part[0][1] + part[1][1] + part[2][1] + part[3][1] + rb[1]) * 0.1f;
    float d2 = (part[0][2] + part[1][2] + part[2][2] + part[3][2] + rb[2]) * 0.2f;
    float d3 = (part[0][3] + part[1][3] + part[2][3] + part[3][3] + rb[3]) * 0.2f;
    const float* r = rin + m * 4;
    float y1 = r[0], x1 = r[1], y2 = r[2], x2 = r[3];
    float h = y2 - y1, wd = x2 - x1;
    float cy = y1 + 0.5f * h + d0 * h;
    float cx = x1 + 0.5f * wd + d1 * wd;
    float nh = h * expf(d2);
    float nw = wd * expf(d3);
    float* ro = rout + m * 4;
    ro[0] = fminf(fmaxf(cy - 0.5f * nh, 0.f), 1024.f);
    ro[1] = fminf(fmaxf(cx - 0.5f * nw, 0.f), 1024.f);
    ro[2] = fminf(fmaxf(cy + 0.5f * nh, 0.f), 1024.f);
    ro[3] = fminf(fmaxf(cx + 0.5f * nw, 0.f), 1024.f);
  }
}

// ---------------------------------------------------------------------------
// FUSED cls-epilogue + softmax + 3-head average. Reads cls split-K partials:
// logit[h][m][n] = sum_s cpart[((s*3+h)*1024+m)*128+n] + cls_b[h*81+n].
// block = 128 threads per roi.
// ---------------------------------------------------------------------------
__global__ void softmax_avg_kernel(const float* __restrict__ Cpart, int S,
                                   const float* __restrict__ cls_b,
                                   float* __restrict__ out)
{
  int m = blockIdx.x, t = threadIdx.x;
  __shared__ float sh[128];
  float pacc = 0.0f;
  for (int h = 0; h < 3; ++h) {
    float x = -3.0e38f;
    if (t < 81) {
      x = cls_b[h * 81 + t];
      for (int s = 0; s < S; ++s)
        x += Cpart[((size_t)(s * 3 + h) * 1024 + m) * 128 + t];
    }
    sh[t] = x; __syncthreads();
    for (int o = 64; o > 0; o >>= 1) { if (t < o) sh[t] = fmaxf(sh[t], sh[t + o]); __syncthreads(); }
    float mx = sh[0]; __syncthreads();
    float e = (t < 81) ? expf(x - mx) : 0.0f;
    sh[t] = e; __syncthreads();
    for (int o = 64; o > 0; o >>= 1) { if (t < o) sh[t] += sh[t + o]; __syncthreads(); }
    float sum = sh[0]; __syncthreads();
    pacc += e / sum;
  }
  if (t < 81) out[(size_t)m * 81 + t] = pacc / 3.0f;
}

// ===========================================================================
extern "C" void kernel_launch(void* const* d_in, const int* in_sizes, int n_in,
                              void* d_out, int out_size, void* d_ws, size_t ws_size,
                              hipStream_t stream)
{
  const float* P2 = (const float*)d_in[0];
  const float* P3 = (const float*)d_in[1];
  const float* P4 = (const float*)d_in[2];
  const float* P5 = (const float*)d_in[3];
  const float* rois = (const float*)d_in[4];
  const float* fc1_w = (const float*)d_in[5];
  const float* fc1_b = (const float*)d_in[6];
  const float* fc2_w = (const float*)d_in[7];
  const float* fc2_b = (const float*)d_in[8];
  const float* cls_w = (const float*)d_in[9];
  const float* cls_b = (const float*)d_in[10];
  const float* reg_w = (const float*)d_in[11];
  const float* reg_b = (const float*)d_in[12];
  float* out = (float*)d_out;

  char* ws = (char*)d_ws;
  size_t off = 0;
  auto alloc = [&](size_t b) -> char* {
    char* p = ws + off;
    off = (off + b + 255) & ~(size_t)255;
    return p;
  };
  unsigned short* w1t_hi = (unsigned short*)alloc(3ull * 1024 * K1 * 2);
  unsigned short* w2t_hi = (unsigned short*)alloc(3ull * 1024 * 1024 * 2);
  unsigned short* w2t_lo = (unsigned short*)alloc(2ull * 1024 * 1024 * 2);
  unsigned short* w3t    = (unsigned short*)alloc(3ull * 128 * 1024 * 2);
  unsigned short* phi    = (unsigned short*)alloc((size_t)MPAD * K1 * 2);
  unsigned short* plo    = (unsigned short*)alloc((size_t)MPAD * K1 * 2);
  unsigned short* h1_hi  = (unsigned short*)alloc(3ull * MPAD * 1024 * 2);
  unsigned short* h1_lo  = (unsigned short*)alloc((size_t)MPAD * 1024 * 2);
  unsigned short* h2_hi  = (unsigned short*)alloc(3ull * MPAD * 1024 * 2);
  float* r1              = (float*)alloc(16384);
  float* r2              = (float*)alloc(16384);
  // w1t_lo LAST: dead after stage 1, so stage-2 partials reuse it + tail.
  const size_t w1lo_bytes = 2ull * 1024 * K1 * 2;
  unsigned short* w1t_lo = (unsigned short*)alloc(w1lo_bytes);

  const size_t SLAB = (size_t)MPAD * 1024 * 4;  // 4 MiB per (s,h) slice
  size_t tail = (ws_size > off) ? (ws_size - off) : 0;

  // stages 0/1 partials in tail; R2-proven sweet spot S=8 (R3's 16 regressed)
  int S01 = (int)(tail / SLAB);
  if (S01 > 8) S01 = 8;
  if (S01 < 1) S01 = 1;
  float* cpart01 = (float*)(ws + off);
  // stage-2 partials alias w1t_lo (51.4 MB): S2=4 needs 48 MiB (R2-proven)
  const int S2 = 4;
  float* cpart2 = (float*)w1t_lo;

  const int fc1Steps01 = (392 + S01 - 1) / S01;
  const int fc2Steps01 = (32 + S01 - 1) / S01;
  const int fc1Steps2 = (392 + S2 - 1) / S2;

  const long long hs1 = (long long)1024 * K1;
  const long long hs2 = (long long)1024 * 1024;

  dim3 b256(256);

  // --- weight conversion (per call) ---
  hipLaunchKernelGGL(transpose_convert, dim3(K1 / 256, 32, 3), b256, 0, stream,
                     fc1_w, w1t_hi, w1t_lo, K1, 1024, 2);
  hipLaunchKernelGGL(transpose_convert, dim3(4, 32, 3), b256, 0, stream,
                     fc2_w, w2t_hi, w2t_lo, 1024, 1024, 2);
  hipLaunchKernelGGL(transpose_cls, dim3(128, 3), b256, 0, stream, cls_w, w3t);
  hipMemsetAsync(phi + (size_t)NROI * K1, 0, (size_t)(MPAD - NROI) * K1 * 2, stream);
  hipMemsetAsync(plo + (size_t)NROI * K1, 0, (size_t)(MPAD - NROI) * K1 * 2, stream);

  // --- stages 0,1: split-precision path, deltas only ---
  for (int st = 0; st < 2; ++st) {
    const float* rin = (st == 0) ? rois : r1;
    float* rout = (st == 0) ? r1 : r2;
    hipLaunchKernelGGL(roi_align_kernel, dim3(NROI), b256, 0, stream,
                       rin, P2, P3, P4, P5, phi, plo, 1);
    hipLaunchKernelGGL((gemm_bf16<true>), dim3(64, S01, 1), b256, 0, stream,
                       phi, plo, 0LL,
                       w1t_hi + (size_t)st * hs1, w1t_lo + (size_t)st * hs1, 0LL,
                       cpart01, 1024, K1, fc1Steps01);
    hipLaunchKernelGGL(epilogue_kernel, dim3(1024), b256, 0, stream,
                       cpart01, S01, 1, 1024, fc1_b + st * 1024,
                       h1_hi, h1_lo, 4);
    hipLaunchKernelGGL((gemm_bf16<true>), dim3(64, S01, 1), b256, 0, stream,
                       h1_hi, h1_lo, 0LL,
                       w2t_hi + (size_t)st * hs2, w2t_lo + (size_t)st * hs2, 0LL,
                       cpart01, 1024, 1024, fc2Steps01);
    // fused: fc2 epilogue + reg head + delta2bbox (fp32 h2, no round-trip)
    hipLaunchKernelGGL(reg_delta_kernel, dim3(NROI), b256, 0, stream,
                       cpart01, S01, fc2_b + st * 1024,
                       reg_w + (size_t)st * 1024 * 4, reg_b + st * 4,
                       rin, rout);
  }

  // --- stage 2: plain bf16, heads 0,1,2 batched via blockIdx.z ---
  hipLaunchKernelGGL(roi_align_kernel, dim3(NROI), b256, 0, stream,
                     r2, P2, P3, P4, P5, phi, plo, 0);
  hipLaunchKernelGGL((gemm_bf16<false>), dim3(64, S2, 3), b256, 0, stream,
                     phi, (const unsigned short*)0, 0LL,
                     w1t_hi, (const unsigned short*)0, hs1,
                     cpart2, 1024, K1, fc1Steps2);
  hipLaunchKernelGGL(epilogue_kernel, dim3(3072), b256, 0, stream,
                     cpart2, S2, 3, 1024, fc1_b,
                     h1_hi, (unsigned short*)0, 0);
  hipLaunchKernelGGL((gemm_bf16<false>), dim3(64, S2, 3), b256, 0, stream,
                     h1_hi, (const unsigned short*)0, hs2,
                     w2t_hi, (const unsigned short*)0, hs2,
                     cpart2, 1024, 1024, (32 + S2 - 1) / S2);
  hipLaunchKernelGGL(epilogue_kernel, dim3(3072), b256, 0, stream,
                     cpart2, S2, 3, 1024, fc2_b,
                     h2_hi, (unsigned short*)0, 0);
  // cls: N=128 (81 real + pad), S=8 -> 192 blocks, 4 steps (12.6 MB partials)
  hipLaunchKernelGGL((gemm_bf16<false>), dim3(8, 8, 3), b256, 0, stream,
                     h2_hi, (const unsigned short*)0, hs2,
                     w3t, (const unsigned short*)0, (long long)128 * 1024,
                     cpart2, 128, 1024, 4);
  // fused: cls epilogue + softmax + 3-head average
  hipLaunchKernelGGL(softmax_avg_kernel, dim3(NROI), dim3(128), 0, stream,
                     cpart2, 8, cls_b, out);
}